// Round 1
// baseline (162.865 us; speedup 1.0000x reference)
//
#include <hip/hip_runtime.h>
#include <math.h>

#define TPB 256
#define EPT 16
#define COLS 4096

__device__ __forceinline__ float wave_sum(float v) {
#pragma unroll
    for (int o = 32; o > 0; o >>= 1) v += __shfl_xor(v, o, 64);
    return v;
}
__device__ __forceinline__ float wave_max(float v) {
#pragma unroll
    for (int o = 32; o > 0; o >>= 1) v = fmaxf(v, __shfl_xor(v, o, 64));
    return v;
}

// Solves per-row: find nu s.t. sum_i w_omega(2*(y_i+nu)-1) = 1, p_i = w_omega(...)
// where w_omega(z): x + e^x = z, p = e^x.  (alpha = 0.5 folded in.)
__global__ __launch_bounds__(TPB) void prox_softmax_kernel(
    const float* __restrict__ X, float* __restrict__ P, int rows)
{
    __shared__ float sred[8];
    const int tid = threadIdx.x;
    const int row = blockIdx.x;
    if (row >= rows) return;

    const float4* __restrict__ x4 = reinterpret_cast<const float4*>(X + (size_t)row * COLS);
    float4* __restrict__ p4 = reinterpret_cast<float4*>(P + (size_t)row * COLS);

    float w[EPT];   // holds y on load, then 2y-1
    float xx[EPT];  // current log-omega
    float u[EPT];   // exp(xx)

    // ---- load (coalesced float4) ----
#pragma unroll
    for (int j = 0; j < 4; ++j) {
        float4 v = x4[tid + j * TPB];
        w[4 * j + 0] = v.x; w[4 * j + 1] = v.y;
        w[4 * j + 2] = v.z; w[4 * j + 3] = v.w;
    }

    // ---- row max ----
    float m = -1e30f;
#pragma unroll
    for (int j = 0; j < EPT; ++j) m = fmaxf(m, w[j]);
    m = wave_max(m);
    const int wid = tid >> 6, lane = tid & 63;
    if (lane == 0) sred[wid] = m;
    __syncthreads();
    m = fmaxf(fmaxf(sred[0], sred[1]), fmaxf(sred[2], sred[3]));
    __syncthreads();

    // ---- LSE-based nu init: sum exp(2(y+nu)-1) = 1  (upper bound on sum omega) ----
    float se = 0.f;
#pragma unroll
    for (int j = 0; j < EPT; ++j) se += __expf(2.f * (w[j] - m));
    se = wave_sum(se);
    if (lane == 0) sred[wid] = se;
    __syncthreads();
    se = (sred[0] + sred[1]) + (sred[2] + sred[3]);
    __syncthreads();
    float nu = 0.5f * (1.f - (2.f * m + __logf(se)));
    nu = fminf(nu, 1.f - m);   // guarantees z = 2(y+nu)-1 <= 1 for cold start

    // ---- w := 2y - 1 ----
#pragma unroll
    for (int j = 0; j < EPT; ++j) w[j] = 2.f * w[j] - 1.f;

    // ---- cold-start Halley init: x0 = min(z, (z-1)/2) ----
#pragma unroll
    for (int j = 0; j < EPT; ++j) {
        float z = fmaf(2.f, nu, w[j]);
        float x0 = fminf(z, 0.5f * (z - 1.f));
        xx[j] = x0;
        u[j] = __expf(x0);
    }

    // Halley sweep over this thread's 16 elements, adaptive iteration count.
    auto halley = [&](int cap) {
        bool more = true;
        int k = 0;
        while (more && k < cap) {
            more = false;
#pragma unroll
            for (int j = 0; j < EPT; ++j) {
                float z = fmaf(2.f, nu, w[j]);
                float uu = u[j];
                float r = z - xx[j] - uu;             // 2*f
                float op = 1.f + uu;
                float xn = xx[j] + __fdividef(r * op, op * op + 0.5f * r * uu);
                xx[j] = xn;
                u[j] = __expf(xn);
                float tol = fmaf(2e-6f, fabsf(z), 1e-5f);
                more |= (fabsf(r) > tol);
            }
            ++k;
        }
    };

    halley(16);

    // ---- Newton on nu:  f = sum(p) - 1,  f' = sum(2p/(1+p)) ----
    for (int it = 0; it < 50; ++it) {
        float s = 0.f, ds = 0.f;
#pragma unroll
        for (int j = 0; j < EPT; ++j) {
            s += u[j];
            ds += __fdividef(u[j], 1.f + u[j]);
        }
        s = wave_sum(s);
        ds = wave_sum(ds);
        if (lane == 0) { sred[wid] = s; sred[4 + wid] = ds; }
        __syncthreads();
        s  = (sred[0] + sred[1]) + (sred[2] + sred[3]);
        ds = (sred[4] + sred[5]) + (sred[6] + sred[7]);
        __syncthreads();

        float f = s - 1.f;
        if (fabsf(f) < 1e-5f) break;          // block-uniform branch

        float dnu = __fdividef(f, 2.f * ds);  // Newton step
        nu -= dnu;

        // warm start: dx = dz/(1+u) = -2*dnu/(1+u), then re-polish
#pragma unroll
        for (int j = 0; j < EPT; ++j) {
            xx[j] -= __fdividef(2.f * dnu, 1.f + u[j]);
            u[j] = __expf(xx[j]);
        }
        halley(8);
    }

    // ---- store p = exp(l) ----
#pragma unroll
    for (int j = 0; j < 4; ++j) {
        float4 v;
        v.x = u[4 * j + 0]; v.y = u[4 * j + 1];
        v.z = u[4 * j + 2]; v.w = u[4 * j + 3];
        p4[tid + j * TPB] = v;
    }
}

extern "C" void kernel_launch(void* const* d_in, const int* in_sizes, int n_in,
                              void* d_out, int out_size, void* d_ws, size_t ws_size,
                              hipStream_t stream) {
    const float* x = (const float*)d_in[0];
    float* out = (float*)d_out;
    int rows = out_size / COLS;
    prox_softmax_kernel<<<rows, TPB, 0, stream>>>(x, out, rows);
}

// Round 2
// 116.742 us; speedup vs baseline: 1.3951x; 1.3951x over previous
//
#include <hip/hip_runtime.h>
#include <math.h>

#define TPB 256
#define EPT 16
#define COLS 4096
#define NWAVE (TPB / 64)

__device__ __forceinline__ float wave_sum(float v) {
#pragma unroll
    for (int o = 32; o > 0; o >>= 1) v += __shfl_xor(v, o, 64);
    return v;
}
__device__ __forceinline__ float wave_max(float v) {
#pragma unroll
    for (int o = 32; o > 0; o >>= 1) v = fmaxf(v, __shfl_xor(v, o, 64));
    return v;
}

// degree-7 Taylor of e^x, accurate for x in [0, ~1.2] (rel err < 3e-6)
__device__ __forceinline__ float exp_poly(float x) {
    float r = fmaf(1.f / 5040.f, x, 1.f / 720.f);
    r = fmaf(r, x, 1.f / 120.f);
    r = fmaf(r, x, 1.f / 24.f);
    r = fmaf(r, x, 1.f / 6.f);
    r = fmaf(r, x, 0.5f);
    r = fmaf(r, x, 1.f);
    r = fmaf(r, x, 1.f);
    return r;
}

// one Halley step toward p = W(t):  g(p) = p*e^p - t = 0   (no HW transcendentals)
__device__ __forceinline__ float halley_w(float p, float t) {
    float e = exp_poly(p);
    float w = p * e;
    float f = w - t;
    float fp = w + e;                               // g' = (p+1)e
    float num = f * fp;
    float den = fmaf(fp, fp, -0.5f * f * (fp + e)); // g'^2 - 0.5 g g''  (g'' = (p+2)e)
    return p - __fdividef(num, den);
}

// Per row: p_i = W(e^{2(y_i+nu)-1}), nu s.t. sum p = 1.  (alpha=0.5 Wright-omega form)
__global__ __launch_bounds__(TPB) void prox_softmax_kernel(
    const float* __restrict__ X, float* __restrict__ P, int rows)
{
    __shared__ float sred[2 * NWAVE];
    const int tid = threadIdx.x;
    const int row = blockIdx.x;
    if (row >= rows) return;
    const int wid = tid >> 6, lane = tid & 63;

    const float4* __restrict__ x4 = reinterpret_cast<const float4*>(X + (size_t)row * COLS);
    float4* __restrict__ p4 = reinterpret_cast<float4*>(P + (size_t)row * COLS);

    float q[EPT], p[EPT];

    // ---- load y (coalesced float4) ----
#pragma unroll
    for (int j = 0; j < 4; ++j) {
        float4 v = x4[tid + j * TPB];
        q[4 * j + 0] = v.x; q[4 * j + 1] = v.y;
        q[4 * j + 2] = v.z; q[4 * j + 3] = v.w;
    }

    // ---- row max ----
    float m = -1e30f;
#pragma unroll
    for (int j = 0; j < EPT; ++j) m = fmaxf(m, q[j]);
    m = wave_max(m);
    if (lane == 0) sred[wid] = m;
    __syncthreads();
    m = fmaxf(fmaxf(sred[0], sred[1]), fmaxf(sred[2], sred[3]));
    __syncthreads();

    // ---- q = exp(2(y-m))  [the ONLY per-element exp];  A = sum q, B = sum q^2 ----
    float A = 0.f, B = 0.f;
#pragma unroll
    for (int j = 0; j < EPT; ++j) {
        float e = __expf(2.f * (q[j] - m));
        q[j] = e;
        A += e;
        B = fmaf(e, e, B);
    }
    A = wave_sum(A); B = wave_sum(B);
    if (lane == 0) { sred[wid] = A; sred[NWAVE + wid] = B; }
    __syncthreads();
    A = (sred[0] + sred[1]) + (sred[2] + sred[3]);
    B = (sred[4] + sred[5]) + (sred[6] + sred[7]);
    __syncthreads();

    // ---- init scale: solve s*A - s^2*B = 1 (i.e. sum(t - t^2) = 1), smaller root ----
    float disc = fmaf(A, A, -4.f * B);
    float d = sqrtf(fmaxf(disc, 0.f));
    float s = __fdividef(2.f, A + d);

    // ---- initial W(t): Pade [1+4/3 t] / [1 + 7/3 t + 5/6 t^2] (exact thru t^4) + 2 Halley ----
#pragma unroll
    for (int j = 0; j < EPT; ++j) {
        float t = q[j] * s;
        float num = t * fmaf(4.f / 3.f, t, 1.f);
        float den = fmaf(t, fmaf(5.f / 6.f, t, 7.f / 3.f), 1.f);
        float pp = __fdividef(num, den);
        pp = halley_w(pp, t);
        pp = halley_w(pp, t);
        p[j] = pp;
    }

    // ---- Newton on nu (multiplicative on s): f = sum p - 1, df = sum 2p/(1+p) ----
    for (int it = 0; it < 12; ++it) {
        float S1 = 0.f, S2 = 0.f;
#pragma unroll
        for (int j = 0; j < EPT; ++j) {
            S1 += p[j];
            S2 += __fdividef(p[j], 1.f + p[j]);
        }
        S1 = wave_sum(S1); S2 = wave_sum(S2);
        if (lane == 0) { sred[wid] = S1; sred[NWAVE + wid] = S2; }
        __syncthreads();
        S1 = (sred[0] + sred[1]) + (sred[2] + sred[3]);
        S2 = (sred[4] + sred[5]) + (sred[6] + sred[7]);
        __syncthreads();

        float f = S1 - 1.f;
        if (fabsf(f) < 1e-5f) break;  // block-uniform

        // dnu = -f/(2*S2);  s *= e^{2*dnu}  (one scalar exp per block)
        float c = __expf(-__fdividef(f, S2));
        s *= c;
#pragma unroll
        for (int j = 0; j < EPT; ++j)
            p[j] = halley_w(p[j], q[j] * s);   // warm-started, 1 step is cubic-accurate
    }

    // ---- store p ----
#pragma unroll
    for (int j = 0; j < 4; ++j) {
        float4 v;
        v.x = p[4 * j + 0]; v.y = p[4 * j + 1];
        v.z = p[4 * j + 2]; v.w = p[4 * j + 3];
        p4[tid + j * TPB] = v;
    }
}

extern "C" void kernel_launch(void* const* d_in, const int* in_sizes, int n_in,
                              void* d_out, int out_size, void* d_ws, size_t ws_size,
                              hipStream_t stream) {
    const float* x = (const float*)d_in[0];
    float* out = (float*)d_out;
    int rows = out_size / COLS;
    prox_softmax_kernel<<<rows, TPB, 0, stream>>>(x, out, rows);
}

// Round 3
// 75.352 us; speedup vs baseline: 2.1614x; 1.5493x over previous
//
#include <hip/hip_runtime.h>
#include <math.h>

#define TPB 256
#define EPT 16
#define COLS 4096
#define NWAVE (TPB / 64)

__device__ __forceinline__ float wave_sum(float v) {
#pragma unroll
    for (int o = 32; o > 0; o >>= 1) v += __shfl_xor(v, o, 64);
    return v;
}

// degree-6 Taylor of e^x, x in [0, ~1.5]
__device__ __forceinline__ float exp_poly(float x) {
    float r = fmaf(1.f / 720.f, x, 1.f / 120.f);
    r = fmaf(r, x, 1.f / 24.f);
    r = fmaf(r, x, 1.f / 6.f);
    r = fmaf(r, x, 0.5f);
    r = fmaf(r, x, 1.f);
    r = fmaf(r, x, 1.f);
    return r;
}

// one Halley step toward p = W(t):  g(p) = p*e^p - t = 0
__device__ __forceinline__ float halley_w(float p, float t) {
    float e = exp_poly(p);
    float w = p * e;
    float f = w - t;
    float fp = w + e;                               // (1+p)e
    float num = f * fp;
    float den = fmaf(fp, fp, -0.5f * f * (fp + e)); // fp^2 - 0.5 f (2+p)e
    return p - __fdividef(num, den);
}

// Pade [2/2] of W(t), exact through t^4
__device__ __forceinline__ float pade_w(float t) {
    float num = t * fmaf(4.f / 3.f, t, 1.f);
    float den = fmaf(t, fmaf(5.f / 6.f, t, 7.f / 3.f), 1.f);
    return __fdividef(num, den);
}

__device__ __forceinline__ void block_red2(float& a, float& b, float* sred, int wid, int lane) {
    a = wave_sum(a); b = wave_sum(b);
    if (lane == 0) { sred[wid] = a; sred[NWAVE + wid] = b; }
    __syncthreads();
    a = (sred[0] + sred[1]) + (sred[2] + sred[3]);
    b = (sred[4] + sred[5]) + (sred[6] + sred[7]);
    __syncthreads();
}

// Per row: p_i = W(e^{2(y_i+nu)-1}) with nu s.t. sum p = 1  (alpha=0.5)
__global__ __launch_bounds__(TPB) void prox_softmax_kernel(
    const float* __restrict__ X, float* __restrict__ P, int rows)
{
    __shared__ float sred[4 * NWAVE];
    const int tid = threadIdx.x;
    const int row = blockIdx.x;
    if (row >= rows) return;
    const int wid = tid >> 6, lane = tid & 63;

    const float4* __restrict__ x4 = reinterpret_cast<const float4*>(X + (size_t)row * COLS);
    float4* __restrict__ p4 = reinterpret_cast<float4*>(P + (size_t)row * COLS);

    float q[EPT], p[EPT], r[EPT];

    // ---- load y ----
#pragma unroll
    for (int j = 0; j < 4; ++j) {
        float4 v = x4[tid + j * TPB];
        q[4 * j + 0] = v.x; q[4 * j + 1] = v.y;
        q[4 * j + 2] = v.z; q[4 * j + 3] = v.w;
    }

    // ---- single exp pass: q = exp(2y); moments A..D ----
    float A = 0.f, B = 0.f, C = 0.f, D = 0.f;
#pragma unroll
    for (int j = 0; j < EPT; ++j) {
        float e = __expf(q[j] + q[j]);
        q[j] = e;
        float e2 = e * e;
        A += e;
        B += e2;
        C = fmaf(e2, e, C);
        D = fmaf(e2, e2, D);
    }
    block_red2(A, B, sred, wid, lane);
    block_red2(C, D, sred, wid, lane);

    // ---- scalar init: quadratic root, then quartic Newton (W series thru t^4) ----
    float disc = fmaf(A, A, -4.f * B);
    float s0 = __fdividef(2.f, A + sqrtf(fmaxf(disc, 0.f)));
    float s = s0;
    const float c3 = 1.5f, c4 = -8.f / 3.f;
#pragma unroll
    for (int k = 0; k < 3; ++k) {
        float g  = fmaf(fmaf(fmaf(fmaf(c4 * D, s, c3 * C), s, -B), s, A), s, -1.f);
        float gp = fmaf(fmaf(fmaf(4.f * c4 * D, s, 3.f * c3 * C), s, -2.f * B), s, A);
        s -= __fdividef(g, gp);
    }
    if (!(s > 0.f && s < 3.4e38f)) s = s0;
    s = fminf(fmaxf(s, 0.25f * s0), 4.f * s0);

    // ---- per-element W eval: Pade + 1 Halley; sums S1, S2 ----
    float S1 = 0.f, S2 = 0.f;
#pragma unroll
    for (int j = 0; j < EPT; ++j) {
        float t = q[j] * s;
        float pp = halley_w(pade_w(t), t);
        p[j] = pp;
        float rr = __fdividef(pp, 1.f + pp);
        r[j] = rr;
        S1 += pp;
        S2 += rr;
    }
    block_red2(S1, S2, sred, wid, lane);
    float f = S1 - 1.f;

    // ---- finish: linear correction (typical) or full Newton loop (rare heavy rows) ----
    for (int it = 0; it < 10; ++it) {
        if (fabsf(f) < 2e-3f) {   // block-uniform
            float dsig = -__fdividef(f, S2);
#pragma unroll
            for (int j = 0; j < EPT; ++j) p[j] = fmaf(r[j], dsig, p[j]);
            break;
        }
        float dsig = -__fdividef(f, S2);
        dsig = fminf(fmaxf(dsig, -1.f), 1.f);
        s *= __expf(dsig);
        S1 = 0.f; S2 = 0.f;
#pragma unroll
        for (int j = 0; j < EPT; ++j) {
            float pp = fmaf(r[j], dsig, p[j]);   // warm start
            float t = q[j] * s;
            pp = halley_w(pp, t);
            pp = halley_w(pp, t);
            p[j] = pp;
            float rr = __fdividef(pp, 1.f + pp);
            r[j] = rr;
            S1 += pp;
            S2 += rr;
        }
        block_red2(S1, S2, sred, wid, lane);
        f = S1 - 1.f;
    }

    // ---- store ----
#pragma unroll
    for (int j = 0; j < 4; ++j) {
        float4 v;
        v.x = p[4 * j + 0]; v.y = p[4 * j + 1];
        v.z = p[4 * j + 2]; v.w = p[4 * j + 3];
        p4[tid + j * TPB] = v;
    }
}

extern "C" void kernel_launch(void* const* d_in, const int* in_sizes, int n_in,
                              void* d_out, int out_size, void* d_ws, size_t ws_size,
                              hipStream_t stream) {
    const float* x = (const float*)d_in[0];
    float* out = (float*)d_out;
    int rows = out_size / COLS;
    prox_softmax_kernel<<<rows, TPB, 0, stream>>>(x, out, rows);
}

// Round 5
// 50.691 us; speedup vs baseline: 3.2129x; 1.4865x over previous
//
#include <hip/hip_runtime.h>
#include <math.h>

#define TPB 256
#define EPT 16
#define COLS 4096
#define NWAVE (TPB / 64)

__device__ __forceinline__ float wave_sum(float v) {
#pragma unroll
    for (int o = 32; o > 0; o >>= 1) v += __shfl_xor(v, o, 64);
    return v;
}
__device__ __forceinline__ float wave_max(float v) {
#pragma unroll
    for (int o = 32; o > 0; o >>= 1) v = fmaxf(v, __shfl_xor(v, o, 64));
    return v;
}
__device__ __forceinline__ void block_red2(float& a, float& b, float* sred, int wid, int lane) {
    a = wave_sum(a); b = wave_sum(b);
    if (lane == 0) { sred[wid] = a; sred[NWAVE + wid] = b; }
    __syncthreads();
    a = (sred[0] + sred[1]) + (sred[2] + sred[3]);
    b = (sred[4] + sred[5]) + (sred[6] + sred[7]);
    __syncthreads();
}
__device__ __forceinline__ float block_redmax(float v, float* sred, int wid, int lane) {
    v = wave_max(v);
    if (lane == 0) sred[wid] = v;
    __syncthreads();
    v = fmaxf(fmaxf(sred[0], sred[1]), fmaxf(sred[2], sred[3]));
    __syncthreads();
    return v;
}

// robust Halley step toward p = W(t), hardware exp (rare path only)
__device__ __forceinline__ float halley_hw(float p, float t) {
    float e = __expf(p);
    float w = p * e;
    float f = w - t;
    float fp = w + e;                                // (1+p)e
    float den = fmaf(fp, fp, -0.5f * f * (fp + e));  // fp^2 - 0.5 f (2+p)e
    return p - __fdividef(f * fp, den);
}

// Per row: p_i = W(e^{2(y_i+nu)-1}), nu s.t. sum p = 1   (alpha = 0.5)
__global__ __launch_bounds__(TPB) void prox_softmax_kernel(
    const float* __restrict__ X, float* __restrict__ P, int rows)
{
    __shared__ float sred[2 * NWAVE];
    const int tid = threadIdx.x;
    const int row = blockIdx.x;
    if (row >= rows) return;
    const int wid = tid >> 6, lane = tid & 63;

    const float4* __restrict__ x4 = reinterpret_cast<const float4*>(X + (size_t)row * COLS);
    float4* __restrict__ p4 = reinterpret_cast<float4*>(P + (size_t)row * COLS);

    float q[EPT], p[EPT];

    // ---- load y ----
#pragma unroll
    for (int j = 0; j < 4; ++j) {
        float4 v = x4[tid + j * TPB];
        q[4 * j + 0] = v.x; q[4 * j + 1] = v.y;
        q[4 * j + 2] = v.z; q[4 * j + 3] = v.w;
    }

    // ---- single transcendental pass: q = exp(2y) = exp2(y * 2/ln2); moments + max ----
    const float C2E = 2.8853900817779268f;  // 2/ln(2)
    float A = 0.f, B = 0.f, C = 0.f, D = 0.f, qm = 0.f;
#pragma unroll
    for (int j = 0; j < EPT; ++j) {
        float e = __builtin_amdgcn_exp2f(q[j] * C2E);
        q[j] = e;
        float e2 = e * e;
        A += e;
        B += e2;
        C = fmaf(e2, e, C);
        D = fmaf(e2, e2, D);
        qm = fmaxf(qm, e);
    }
    block_red2(A, B, sred, wid, lane);
    block_red2(C, D, sred, wid, lane);
    qm = block_redmax(qm, sred, wid, lane);

    // ---- scalar init: quadratic root then quartic Newton (W series thru t^4) ----
    float disc = fmaf(A, A, -4.f * B);
    float s0 = __fdividef(2.f, A + sqrtf(fmaxf(disc, 0.f)));
    float s = s0;
    const float c3 = 1.5f, c4 = -8.f / 3.f;
#pragma unroll
    for (int k = 0; k < 3; ++k) {
        float g  = fmaf(fmaf(fmaf(fmaf(c4 * D, s, c3 * C), s, -B), s, A), s, -1.f);
        float gp = fmaf(fmaf(fmaf(4.f * c4 * D, s, 3.f * c3 * C), s, -2.f * B), s, A);
        s -= __fdividef(g, gp);
    }
    if (!(s > 0.f && s < 3.4e38f)) s = s0;
    s = fminf(fmaxf(s, 0.25f * s0), 4.f * s0);

    // ---- fast eval: W series thru t^7 (no divides), r ~ p(1-p+p^2) ----
    float S1 = 0.f, S2 = 0.f;
#pragma unroll
    for (int j = 0; j < EPT; ++j) {
        float t = q[j] * s;
        float acc = fmaf(23.343054f, t, -10.8f);      // c7, c6
        acc = fmaf(acc, t, 125.f / 24.f);             // c5
        acc = fmaf(acc, t, -8.f / 3.f);               // c4
        acc = fmaf(acc, t, 1.5f);                     // c3
        acc = fmaf(acc, t, -1.f);                     // c2
        acc = fmaf(acc, t, 1.f);                      // c1
        float pp = t * acc;
        p[j] = pp;
        float rr = pp * fmaf(pp, pp - 1.f, 1.f);      // p - p^2 + p^3
        S1 += pp;
        S2 += rr;
    }
    block_red2(S1, S2, sred, wid, lane);
    float f = S1 - 1.f;
    float tmax = qm * s;

    if ((tmax < 0.22f) && (fabsf(f) < 5e-3f)) {
        // ---- typical: single scalar Newton step, linear per-element correction ----
        float dsig = -__fdividef(f, S2);
#pragma unroll
        for (int j = 0; j < EPT; ++j) {
            float pp = p[j];
            float rr = pp * fmaf(pp, pp - 1.f, 1.f);
            p[j] = fmaf(rr, dsig, pp);
        }
    } else {
        // ---- rare heavy rows: robust hardware-exp Halley + nu-Newton ----
#pragma unroll
        for (int j = 0; j < EPT; ++j)
            p[j] = __logf(1.f + q[j] * s);            // upper bound on W(t)
        for (int it = 0; it < 10; ++it) {
            S1 = 0.f; S2 = 0.f;
#pragma unroll
            for (int j = 0; j < EPT; ++j) {
                float t = q[j] * s;
                float pp = halley_hw(p[j], t);
                pp = halley_hw(pp, t);
                p[j] = pp;
                S1 += pp;
                S2 += __fdividef(pp, 1.f + pp);
            }
            block_red2(S1, S2, sred, wid, lane);
            f = S1 - 1.f;
            if (fabsf(f) < 2e-5f) break;              // block-uniform
            float dsig = fminf(fmaxf(-__fdividef(f, S2), -1.f), 1.f);
            s *= __expf(dsig);
        }
    }

    // ---- store ----
#pragma unroll
    for (int j = 0; j < 4; ++j) {
        float4 v;
        v.x = p[4 * j + 0]; v.y = p[4 * j + 1];
        v.z = p[4 * j + 2]; v.w = p[4 * j + 3];
        p4[tid + j * TPB] = v;
    }
}

extern "C" void kernel_launch(void* const* d_in, const int* in_sizes, int n_in,
                              void* d_out, int out_size, void* d_ws, size_t ws_size,
                              hipStream_t stream) {
    const float* x = (const float*)d_in[0];
    float* out = (float*)d_out;
    int rows = out_size / COLS;
    prox_softmax_kernel<<<rows, TPB, 0, stream>>>(x, out, rows);
}

// Round 7
// 49.908 us; speedup vs baseline: 3.2633x; 1.0157x over previous
//
#include <hip/hip_runtime.h>
#include <math.h>

#define TPB 256
#define EPT 16
#define COLS 4096
#define NWAVE (TPB / 64)

typedef float vfloat4 __attribute__((ext_vector_type(4)));

__device__ __forceinline__ float wave_sum(float v) {
#pragma unroll
    for (int o = 32; o > 0; o >>= 1) v += __shfl_xor(v, o, 64);
    return v;
}
__device__ __forceinline__ float wave_max(float v) {
#pragma unroll
    for (int o = 32; o > 0; o >>= 1) v = fmaxf(v, __shfl_xor(v, o, 64));
    return v;
}
__device__ __forceinline__ void block_red2(float& a, float& b, float* sred, int wid, int lane) {
    a = wave_sum(a); b = wave_sum(b);
    if (lane == 0) { sred[wid] = a; sred[NWAVE + wid] = b; }
    __syncthreads();
    a = (sred[0] + sred[1]) + (sred[2] + sred[3]);
    b = (sred[4] + sred[5]) + (sred[6] + sred[7]);
    __syncthreads();
}
// combined block reduce: a summed, b maxed
__device__ __forceinline__ void block_red_summax(float& a, float& b, float* sred, int wid, int lane) {
    a = wave_sum(a); b = wave_max(b);
    if (lane == 0) { sred[wid] = a; sred[NWAVE + wid] = b; }
    __syncthreads();
    a = (sred[0] + sred[1]) + (sred[2] + sred[3]);
    b = fmaxf(fmaxf(sred[4], sred[5]), fmaxf(sred[6], sred[7]));
    __syncthreads();
}

// robust Halley step toward p = W(t), hardware exp (rare path only)
__device__ __forceinline__ float halley_hw(float p, float t) {
    float e = __expf(p);
    float w = p * e;
    float f = w - t;
    float fp = w + e;                                // (1+p)e
    float den = fmaf(fp, fp, -0.5f * f * (fp + e));  // fp^2 - 0.5 f (2+p)e
    return p - __fdividef(f * fp, den);
}

// Per row: p_i = W(e^{2(y_i+nu)-1}), nu s.t. sum p = 1   (alpha = 0.5)
__global__ __launch_bounds__(TPB) void prox_softmax_kernel(
    const float* __restrict__ X, float* __restrict__ P, int rows)
{
    __shared__ float sred[2 * NWAVE];
    const int tid = threadIdx.x;
    const int row = blockIdx.x;
    if (row >= rows) return;
    const int wid = tid >> 6, lane = tid & 63;

    const float4* __restrict__ x4 = reinterpret_cast<const float4*>(X + (size_t)row * COLS);
    vfloat4* __restrict__ p4 = reinterpret_cast<vfloat4*>(P + (size_t)row * COLS);

    float q[EPT], p[EPT];

    // ---- load y ----
#pragma unroll
    for (int j = 0; j < 4; ++j) {
        float4 v = x4[tid + j * TPB];
        q[4 * j + 0] = v.x; q[4 * j + 1] = v.y;
        q[4 * j + 2] = v.z; q[4 * j + 3] = v.w;
    }

    // ---- single transcendental pass: q = exp(2y) = exp2(y*2/ln2); moments A,B,C + max ----
    const float C2E = 2.8853900817779268f;  // 2/ln(2)
    float A = 0.f, B = 0.f, C = 0.f, qm = 0.f;
#pragma unroll
    for (int j = 0; j < EPT; ++j) {
        float e = __builtin_amdgcn_exp2f(q[j] * C2E);
        q[j] = e;
        float e2 = e * e;
        A += e;
        B += e2;
        C = fmaf(e2, e, C);
        qm = fmaxf(qm, e);
    }
    block_red2(A, B, sred, wid, lane);
    block_red_summax(C, qm, sred, wid, lane);

    // ---- scalar init: quadratic root then cubic Newton (W series thru t^3) ----
    float disc = fmaf(A, A, -4.f * B);
    float s0 = __fdividef(2.f, A + sqrtf(fmaxf(disc, 0.f)));
    float s = s0;
#pragma unroll
    for (int k = 0; k < 3; ++k) {
        float g  = fmaf(fmaf(fmaf(1.5f * C, s, -B), s, A), s, -1.f);
        float gp = fmaf(fmaf(4.5f * C, s, -2.f * B), s, A);
        s -= __fdividef(g, gp);
    }
    if (!(s > 0.f && s < 3.4e38f)) s = s0;
    s = fminf(fmaxf(s, 0.25f * s0), 4.f * s0);

    // ---- fast eval: W series thru t^7 (no divides), r ~ p(1-p+p^2) ----
    float S1 = 0.f, S2 = 0.f;
#pragma unroll
    for (int j = 0; j < EPT; ++j) {
        float t = q[j] * s;
        float acc = fmaf(23.343054f, t, -10.8f);      // c7, c6
        acc = fmaf(acc, t, 125.f / 24.f);             // c5
        acc = fmaf(acc, t, -8.f / 3.f);               // c4
        acc = fmaf(acc, t, 1.5f);                     // c3
        acc = fmaf(acc, t, -1.f);                     // c2
        acc = fmaf(acc, t, 1.f);                      // c1
        float pp = t * acc;
        p[j] = pp;
        float rr = pp * fmaf(pp, pp - 1.f, 1.f);      // p - p^2 + p^3
        S1 += pp;
        S2 += rr;
    }
    block_red2(S1, S2, sred, wid, lane);
    float f = S1 - 1.f;
    float tmax = qm * s;

    if ((tmax < 0.22f) && (fabsf(f) < 5e-3f)) {
        // ---- typical: single scalar Newton step, linear per-element correction ----
        float dsig = -__fdividef(f, S2);
#pragma unroll
        for (int j = 0; j < EPT; ++j) {
            float pp = p[j];
            float rr = pp * fmaf(pp, pp - 1.f, 1.f);
            p[j] = fmaf(rr, dsig, pp);
        }
    } else {
        // ---- rare heavy rows: robust hardware-exp Halley + nu-Newton ----
#pragma unroll
        for (int j = 0; j < EPT; ++j)
            p[j] = __logf(1.f + q[j] * s);            // upper bound on W(t)
        for (int it = 0; it < 10; ++it) {
            S1 = 0.f; S2 = 0.f;
#pragma unroll
            for (int j = 0; j < EPT; ++j) {
                float t = q[j] * s;
                float pp = halley_hw(p[j], t);
                pp = halley_hw(pp, t);
                p[j] = pp;
                S1 += pp;
                S2 += __fdividef(pp, 1.f + pp);
            }
            block_red2(S1, S2, sred, wid, lane);
            f = S1 - 1.f;
            if (fabsf(f) < 2e-5f) break;              // block-uniform
            float dsig = fminf(fmaxf(-__fdividef(f, S2), -1.f), 1.f);
            s *= __expf(dsig);
        }
    }

    // ---- store (non-temporal: write-once stream, keep input resident in L3) ----
#pragma unroll
    for (int j = 0; j < 4; ++j) {
        vfloat4 v;
        v.x = p[4 * j + 0]; v.y = p[4 * j + 1];
        v.z = p[4 * j + 2]; v.w = p[4 * j + 3];
        __builtin_nontemporal_store(v, &p4[tid + j * TPB]);
    }
}

extern "C" void kernel_launch(void* const* d_in, const int* in_sizes, int n_in,
                              void* d_out, int out_size, void* d_ws, size_t ws_size,
                              hipStream_t stream) {
    const float* x = (const float*)d_in[0];
    float* out = (float*)d_out;
    int rows = out_size / COLS;
    prox_softmax_kernel<<<rows, TPB, 0, stream>>>(x, out, rows);
}